// Round 3
// baseline (963.560 us; speedup 1.0000x reference)
//
#include <hip/hip_runtime.h>

typedef unsigned short u16;
typedef unsigned int   u32;
typedef __bf16 bf16_t;
typedef bf16_t bf16x8 __attribute__((ext_vector_type(8)));
typedef float  f32x4  __attribute__((ext_vector_type(4)));

__device__ __forceinline__ float b2f(u16 u) {
  union { float f; u32 i; } v; v.i = ((u32)u) << 16; return v.f;
}
__device__ __forceinline__ u16 f2b(float f) {
  union { float f; u32 i; } v; v.f = f;
  u32 r = v.i + 0x7FFFu + ((v.i >> 16) & 1u);
  return (u16)(r >> 16);
}
// store/load with either f32 or bf16 backing
__device__ __forceinline__ void stv(u16* p, float v)   { *p = f2b(v); }
__device__ __forceinline__ void stv(float* p, float v) { *p = v; }
__device__ __forceinline__ void ld4(const float* p, float* o) {
  const float4 v = *(const float4*)p; o[0]=v.x; o[1]=v.y; o[2]=v.z; o[3]=v.w;
}
__device__ __forceinline__ void ld4(const u16* p, float* o) {
  union { ushort4 v; u16 e[4]; } u; u.v = *(const ushort4*)p;
#pragma unroll
  for (int k = 0; k < 4; ++k) o[k] = b2f(u.e[k]);
}

// ---------------------------------------------------------------------------
// Prep: weight f32->bf16 conversion; W2 = proj_w @ out_w (bf16);
// b2 = proj_w @ out_b + proj_b (f32).
// ---------------------------------------------------------------------------
__global__ void conv_w(const float* __restrict__ src, u16* __restrict__ dst, int n) {
  const int i = blockIdx.x * 256 + threadIdx.x;
  if (i < n) dst[i] = f2b(src[i]);
}

__global__ void prep_w2(const float* __restrict__ proj_w, const float* __restrict__ out_w,
                        u16* __restrict__ W2) {
  const int o = blockIdx.x, c = threadIdx.x;
  float acc = 0.f;
  for (int m = 0; m < 256; ++m)
    acc += proj_w[o*256 + m] * out_w[m*256 + c];
  W2[o*256 + c] = f2b(acc);
}

__global__ void prep_b2(const float* __restrict__ proj_w, const float* __restrict__ out_b,
                        const float* __restrict__ proj_b, float* __restrict__ b2v) {
  const int o = threadIdx.x;
  float acc = proj_b[o];
  for (int m = 0; m < 256; ++m) acc += proj_w[o*256 + m] * out_b[m];
  b2v[o] = acc;
}

// ---------------------------------------------------------------------------
// LN1 over C + shifted window partition. Block = half a (b,h) row (32 w).
// Writes token-major xn_tok[tok][c] (bf16) and residual x_tok[tok][c].
// ---------------------------------------------------------------------------
template<typename XT>
__global__ __launch_bounds__(256, 2)
void ln1_kernel(const float* __restrict__ x, const float* __restrict__ g,
                const float* __restrict__ bb, u16* __restrict__ xn_tok,
                XT* __restrict__ x_tok) {
  const int bx = blockIdx.x;                 // 128: h*2 + half
  const int h = bx >> 1, w0 = (bx & 1) << 5;
  const int b = blockIdx.y;
  const int tid = threadIdx.x;
  __shared__ float X[256][33];               // 33.8 KB; reads (c+w)%32 -> 2-way free
  __shared__ float ps[8][32], pq[8][32];
  __shared__ float mu_s[32], rs_s[32];
  const int w = tid & 31, cg = tid >> 5;     // 8 channel groups
  float sum = 0.f, sq = 0.f;
  const float* xb = x + ((size_t)b * 256) * 4096 + h * 64 + w0;
  for (int i = 0; i < 32; ++i) {
    const int c = i*8 + cg;
    const float v = xb[(size_t)c * 4096 + w];     // 128B per half-wave
    X[c][w] = v; sum += v; sq += v*v;
  }
  ps[cg][w] = sum; pq[cg][w] = sq;
  __syncthreads();
  if (tid < 32) {
    float s = 0.f, q2 = 0.f;
#pragma unroll
    for (int j = 0; j < 8; ++j) { s += ps[j][tid]; q2 += pq[j][tid]; }
    const float mu = s * (1.f/256.f);
    mu_s[tid] = mu;
    rs_s[tid] = rsqrtf(fmaxf(q2 * (1.f/256.f) - mu*mu, 0.f) + 1e-6f);
  }
  __syncthreads();
  const int c = tid;
  const float gc = g[c], bc = bb[c];
  const int hp = (h + 60) & 63;              // rolled row: h' = (h-4) mod 64
  const int wi = hp >> 3, tr = hp & 7;
  const int tokb = (b << 6) + (wi << 3);
  for (int w2 = 0; w2 < 32; ++w2) {
    const int wp = (w0 + w2 + 60) & 63;
    const int tok = (tokb + (wp >> 3)) * 64 + tr*8 + (wp & 7);
    const float v = X[c][w2];
    xn_tok[(size_t)tok * 256 + c] = f2b((v - mu_s[w2]) * rs_s[w2] * gc + bc);
    stv(&x_tok[(size_t)tok * 256 + c], v);
  }
}

// ---------------------------------------------------------------------------
// MFMA GEMM: C[M,N] = A[M,K] @ W[N,K]^T (+bias; +gelu | +residual).
// A, W bf16; bias f32; res/out f32 or bf16. 128x128 tile, BK=64, 4 waves,
// XOR-swizzled LDS chunks (writes conflict-free, reads 2-way = free, m136).
// ---------------------------------------------------------------------------
constexpr int EPI_BIAS = 0, EPI_GELU = 1, EPI_RES = 2;

template<int N, int K, int EPI, typename OutT, typename ResT>
__global__ __launch_bounds__(256, 2)
void gemm_bt(const u16* __restrict__ A, const u16* __restrict__ W,
             const float* __restrict__ bias, const ResT* __restrict__ res,
             OutT* __restrict__ C) {
  __shared__ u16 As[128*64];
  __shared__ u16 Ws[128*64];
  const int tid = threadIdx.x;
  const int lane = tid & 63;
  const int wave = tid >> 6;
  const int wm = (wave >> 1) << 6;
  const int wn = (wave & 1) << 6;
  const int bm = blockIdx.x, bn = blockIdx.y;
  const u16* Ab = A + (size_t)bm * 128 * K;
  const u16* Wb = W + (size_t)bn * 128 * K;
  f32x4 acc[4][4] = {};

  for (int kb = 0; kb < K; kb += 64) {
    uint4 av[4], wv4[4];
#pragma unroll
    for (int e = 0; e < 4; ++e) {
      const int f = e*256 + tid;          // chunk id: row r, chunk c
      const int r = f >> 3, c = f & 7;
      av[e]  = *(const uint4*)(Ab + (size_t)r*K + kb + c*8);
      wv4[e] = *(const uint4*)(Wb + (size_t)r*K + kb + c*8);
    }
    __syncthreads();                      // previous iter's frag reads done
#pragma unroll
    for (int e = 0; e < 4; ++e) {
      const int f = e*256 + tid;
      const int r = f >> 3, c = f & 7;
      const int p = c ^ (r & 7);          // swizzled position
      *(uint4*)(As + r*64 + p*8) = av[e];
      *(uint4*)(Ws + r*64 + p*8) = wv4[e];
    }
    __syncthreads();
#pragma unroll
    for (int ks = 0; ks < 2; ++ks) {
      bf16x8 af[4], wf[4];
#pragma unroll
      for (int i = 0; i < 4; ++i) {
        const int ra = wm + i*16 + (lane & 15);
        const int pa = ((ks<<2) + (lane >> 4)) ^ (ra & 7);
        af[i] = *(const bf16x8*)(As + ra*64 + pa*8);
        const int rb = wn + i*16 + (lane & 15);
        const int pb = ((ks<<2) + (lane >> 4)) ^ (rb & 7);
        wf[i] = *(const bf16x8*)(Ws + rb*64 + pb*8);
      }
#pragma unroll
      for (int i = 0; i < 4; ++i)
#pragma unroll
        for (int j = 0; j < 4; ++j)
          acc[i][j] = __builtin_amdgcn_mfma_f32_16x16x32_bf16(af[i], wf[j], acc[i][j], 0, 0, 0);
    }
  }
  // Epilogue. C/D layout: col = lane&15, row = (lane>>4)*4 + r  (m89/m91).
  const int row0 = bm*128 + wm + ((lane >> 4) << 2);
  const int col0 = bn*128 + wn + (lane & 15);
#pragma unroll
  for (int j = 0; j < 4; ++j) {
    const int col = col0 + j*16;
    const float bv = bias[col];
#pragma unroll
    for (int i = 0; i < 4; ++i) {
#pragma unroll
      for (int r = 0; r < 4; ++r) {
        const int row = row0 + i*16 + r;
        float v = acc[i][j][r] + bv;
        if constexpr (EPI == EPI_GELU)
          v = 0.5f * v * (1.f + erff(v * 0.7071067811865475f));
        if constexpr (EPI == EPI_RES) {
          float rv; { const ResT* rp = res + (size_t)row * N + col;
                      if constexpr (sizeof(ResT) == 2) rv = b2f(*(const u16*)rp); else rv = *(const float*)rp; }
          v += rv;
        }
        stv(&C[(size_t)row * N + col], v);
      }
    }
  }
}

// ---------------------------------------------------------------------------
// Attention: one block per (window, head). MFMA QK^T -> softmax (shfl) ->
// P via LDS (m120 layout-change pattern) -> MFMA PV. All bf16 in/out.
// ---------------------------------------------------------------------------
__global__ __launch_bounds__(256, 2)
void attn_kernel(const u16* __restrict__ qkv, u16* __restrict__ attn) {
  const int h = blockIdx.x;       // head
  const int n = blockIdx.y;       // window
  const int tid = threadIdx.x;
  const int lane = tid & 63, wv = tid >> 6;
  __shared__ u16 Qs[64*40];
  __shared__ u16 Ks[64*40];
  __shared__ u16 Vt[32*72];       // V transposed [d][t]
  __shared__ u16 Ps[64*72];
  {
    const int row = tid >> 2, ch = tid & 3;
    const u16* base = qkv + (size_t)(n*64 + row) * 768 + h*32 + ch*8;
    *(uint4*)(Qs + row*40 + ch*8) = *(const uint4*)(base);
    *(uint4*)(Ks + row*40 + ch*8) = *(const uint4*)(base + 256);
    union { uint4 v; u16 e[8]; } tmp;
    tmp.v = *(const uint4*)(base + 512);
#pragma unroll
    for (int j = 0; j < 8; ++j) Vt[(ch*8 + j)*72 + row] = tmp.e[j];
  }
  __syncthreads();
  const int mrow = (wv << 4) + (lane & 15);
  const int q4 = lane >> 4;
  f32x4 s[4];
  {
    bf16x8 qa = *(const bf16x8*)(Qs + mrow*40 + q4*8);
#pragma unroll
    for (int nt = 0; nt < 4; ++nt) {
      bf16x8 kb = *(const bf16x8*)(Ks + (nt*16 + (lane & 15))*40 + q4*8);
      f32x4 z = {0.f, 0.f, 0.f, 0.f};
      s[nt] = __builtin_amdgcn_mfma_f32_16x16x32_bf16(qa, kb, z, 0, 0, 0);
    }
  }
  // softmax rows: D row = q4*4+r, col = lane&15; row group = 16 lanes (same q4).
  float pr[4][4];
#pragma unroll
  for (int r = 0; r < 4; ++r) {
    float m0 = fmaxf(fmaxf(s[0][r], s[1][r]), fmaxf(s[2][r], s[3][r]));
    m0 = fmaxf(m0, __shfl_xor(m0, 1, 64));
    m0 = fmaxf(m0, __shfl_xor(m0, 2, 64));
    m0 = fmaxf(m0, __shfl_xor(m0, 4, 64));
    m0 = fmaxf(m0, __shfl_xor(m0, 8, 64));
    const float cs = 0.25500526571944696f;  // log2(e)/sqrt(32)
    float p0 = exp2f(fminf((s[0][r] - m0) * cs, 0.f));
    float p1 = exp2f(fminf((s[1][r] - m0) * cs, 0.f));
    float p2 = exp2f(fminf((s[2][r] - m0) * cs, 0.f));
    float p3 = exp2f(fminf((s[3][r] - m0) * cs, 0.f));
    float sum = p0 + p1 + p2 + p3;
    sum += __shfl_xor(sum, 1, 64);
    sum += __shfl_xor(sum, 2, 64);
    sum += __shfl_xor(sum, 4, 64);
    sum += __shfl_xor(sum, 8, 64);
    const float inv = 1.f / sum;
    pr[0][r] = p0*inv; pr[1][r] = p1*inv; pr[2][r] = p2*inv; pr[3][r] = p3*inv;
  }
  {
    const int c = lane & 15;
#pragma unroll
    for (int nt = 0; nt < 4; ++nt)
#pragma unroll
      for (int r = 0; r < 4; ++r)
        Ps[((wv<<4) + (q4<<2) + r)*72 + nt*16 + c] = f2b(pr[nt][r]);
  }
  __syncthreads();
  f32x4 o0 = {0.f,0.f,0.f,0.f}, o1 = {0.f,0.f,0.f,0.f};
#pragma unroll
  for (int ks = 0; ks < 2; ++ks) {
    bf16x8 pa = *(const bf16x8*)(Ps + mrow*72 + ks*32 + q4*8);
    bf16x8 v0 = *(const bf16x8*)(Vt + (lane & 15)*72 + ks*32 + q4*8);
    bf16x8 v1 = *(const bf16x8*)(Vt + (16 + (lane & 15))*72 + ks*32 + q4*8);
    o0 = __builtin_amdgcn_mfma_f32_16x16x32_bf16(pa, v0, o0, 0, 0, 0);
    o1 = __builtin_amdgcn_mfma_f32_16x16x32_bf16(pa, v1, o1, 0, 0, 0);
  }
  {
    const int c = lane & 15;
    u16* ob = attn + (size_t)(n*64 + (wv<<4) + (q4<<2)) * 256 + h*32;
#pragma unroll
    for (int r = 0; r < 4; ++r) {
      ob[(size_t)r*256 + c]      = f2b(o0[r]);
      ob[(size_t)r*256 + 16 + c] = f2b(o1[r]);
    }
  }
}

// ---------------------------------------------------------------------------
// LN2: token-major rows, one wave per token. y (f32|bf16) -> zn bf16.
// ---------------------------------------------------------------------------
template<typename YT>
__global__ __launch_bounds__(256, 4)
void ln2_kernel(const YT* __restrict__ y, const float* __restrict__ g,
                const float* __restrict__ bb, u16* __restrict__ zn) {
  const int t = blockIdx.x * 4 + (threadIdx.x >> 6);
  const int lane = threadIdx.x & 63;
  float f[4];
  ld4(y + (size_t)t*256 + lane*4, f);
  float sum = f[0]+f[1]+f[2]+f[3];
  float sq  = f[0]*f[0]+f[1]*f[1]+f[2]*f[2]+f[3]*f[3];
#pragma unroll
  for (int d = 32; d; d >>= 1) { sum += __shfl_xor(sum, d, 64); sq += __shfl_xor(sq, d, 64); }
  const float mu = sum * (1.f/256.f);
  const float rs = rsqrtf(fmaxf(sq * (1.f/256.f) - mu*mu, 0.f) + 1e-6f);
  const float4 gv = *(const float4*)(g + lane*4);
  const float4 bv = *(const float4*)(bb + lane*4);
  union { ushort4 v; u16 e[4]; } ov;
  ov.e[0] = f2b((f[0]-mu)*rs*gv.x + bv.x);
  ov.e[1] = f2b((f[1]-mu)*rs*gv.y + bv.y);
  ov.e[2] = f2b((f[2]-mu)*rs*gv.z + bv.z);
  ov.e[3] = f2b((f[3]-mu)*rs*gv.w + bv.w);
  *(ushort4*)(zn + (size_t)t*256 + lane*4) = ov.v;
}

// ---------------------------------------------------------------------------
// Final: out = y + z2 (token-major, f32 accumulate) scattered back to image
// layout (reverse shift) via LDS transpose. Block = half window (32 tokens).
// ---------------------------------------------------------------------------
template<typename YT>
__global__ __launch_bounds__(256, 2)
void final_kernel(const YT* __restrict__ y, const u16* __restrict__ z2,
                  float* __restrict__ out) {
  const int nb = blockIdx.x;              // 2048: window*2 + half
  const int n = nb >> 1, half = nb & 1;
  const int b = n >> 6, wi = (n >> 3) & 7, wj = n & 7;
  const int tid = threadIdx.x;
  __shared__ float S[256][33];            // [channel][local token]
#pragma unroll
  for (int i = 0; i < 4; ++i) {
    const int flat = i*256 + tid;         // [0,1024)
    const int tl = flat >> 5, ch8 = flat & 31;
    const size_t off = (size_t)(n*64 + half*32 + tl) * 256 + ch8*8;
    float yv[8];
    ld4(y + off, yv); ld4(y + off + 4, yv + 4);
    union { uint4 v; u16 e[8]; } zv; zv.v = *(const uint4*)(z2 + off);
#pragma unroll
    for (int k = 0; k < 8; ++k)
      S[ch8*8 + k][tl] = yv[k] + b2f(zv.e[k]);
  }
  __syncthreads();
  const int c = tid;
  float* ob = out + ((size_t)(b*256 + c)) * 4096;
  const int w0 = (wj << 3) + 4;
  const int w1 = ((wj << 3) + 8) & 63;
#pragma unroll
  for (int trl = 0; trl < 4; ++trl) {
    const int hh = ((wi << 3) + (half << 2) + trl + 4) & 63;
    float4 p0, p1;
    p0.x = S[c][trl*8+0]; p0.y = S[c][trl*8+1]; p0.z = S[c][trl*8+2]; p0.w = S[c][trl*8+3];
    p1.x = S[c][trl*8+4]; p1.y = S[c][trl*8+5]; p1.z = S[c][trl*8+6]; p1.w = S[c][trl*8+7];
    *(float4*)(ob + hh*64 + w0) = p0;
    *(float4*)(ob + hh*64 + w1) = p1;
  }
}

// ---------------------------------------------------------------------------
extern "C" void kernel_launch(void* const* d_in, const int* in_sizes, int n_in,
                              void* d_out, int out_size, void* d_ws, size_t ws_size,
                              hipStream_t stream) {
  const float* x       = (const float*)d_in[0];
  const float* norm1_g = (const float*)d_in[1];
  const float* norm1_b = (const float*)d_in[2];
  const float* in_w    = (const float*)d_in[3];
  const float* in_b    = (const float*)d_in[4];
  const float* out_w   = (const float*)d_in[5];
  const float* out_b   = (const float*)d_in[6];
  const float* proj_w  = (const float*)d_in[7];
  const float* proj_b  = (const float*)d_in[8];
  const float* norm2_g = (const float*)d_in[9];
  const float* norm2_b = (const float*)d_in[10];
  const float* fc1_w   = (const float*)d_in[11];
  const float* fc1_b   = (const float*)d_in[12];
  const float* fc2_w   = (const float*)d_in[13];
  const float* fc2_b   = (const float*)d_in[14];
  float* out = (float*)d_out;

  const size_t NTOK = 65536, NCH = 256;
  const size_t nA = NTOK * NCH;           // 16,777,216 elements

  char* base = (char*)d_ws;
  const bool big = ws_size >= 303563776ull;   // tier A: f32 residual/y

  // Shared bf16 buffers (both tiers):
  // B  : xn_tok -> attn-out -> z2   (bf16, nA)
  // Cb : qkv (nA*3) -> h1 (nA*4)    (bf16)
  u16 *B, *Cb, *Wbuf; float *b2v;
  void *Aptr, *Dptr;                      // x_tok, y
  if (big) {
    Aptr = base;                          // f32 x_tok
    B    = (u16*)(base + nA*4);
    Cb   = (u16*)(base + nA*4 + nA*2);
    Dptr = base + nA*4 + nA*2 + nA*8;     // f32 y
    Wbuf = (u16*)(base + nA*4 + nA*2 + nA*8 + nA*4);
  } else {
    Aptr = base;                          // bf16 x_tok
    B    = (u16*)(base + nA*2);
    Cb   = (u16*)(base + nA*2 + nA*2);
    Dptr = base + nA*2 + nA*2 + nA*8;     // bf16 y
    Wbuf = (u16*)(base + nA*2 + nA*2 + nA*8 + nA*2);
  }
  u16* W2    = Wbuf;                      // 65536
  u16* inw_h = Wbuf + 65536;              // 196608
  u16* fc1_h = inw_h + 196608;            // 262144
  u16* fc2_h = fc1_h + 262144;            // 262144
  b2v = (float*)(fc2_h + 262144);         // 256 f32

  // Weight prep
  conv_w<<<768, 256, 0, stream>>>(in_w, inw_h, 196608);
  conv_w<<<1024, 256, 0, stream>>>(fc1_w, fc1_h, 262144);
  conv_w<<<1024, 256, 0, stream>>>(fc2_w, fc2_h, 262144);
  prep_w2<<<256, 256, 0, stream>>>(proj_w, out_w, W2);
  prep_b2<<<1, 256, 0, stream>>>(proj_w, out_b, proj_b, b2v);

  if (big) {
    float* A = (float*)Aptr; float* D = (float*)Dptr;
    ln1_kernel<float><<<dim3(128, 16), 256, 0, stream>>>(x, norm1_g, norm1_b, B, A);
    gemm_bt<768, 256, EPI_BIAS, u16, float><<<dim3(512, 6), 256, 0, stream>>>(B, inw_h, in_b, nullptr, Cb);
    attn_kernel<<<dim3(8, 1024), 256, 0, stream>>>(Cb, B);
    gemm_bt<256, 256, EPI_RES, float, float><<<dim3(512, 2), 256, 0, stream>>>(B, W2, b2v, A, D);
    ln2_kernel<float><<<16384, 256, 0, stream>>>(D, norm2_g, norm2_b, B);
    gemm_bt<1024, 256, EPI_GELU, u16, float><<<dim3(512, 8), 256, 0, stream>>>(B, fc1_h, fc1_b, nullptr, Cb);
    gemm_bt<256, 1024, EPI_BIAS, u16, float><<<dim3(512, 2), 256, 0, stream>>>(Cb, fc2_h, fc2_b, nullptr, B);
    final_kernel<float><<<2048, 256, 0, stream>>>(D, B, out);
  } else {
    u16* A = (u16*)Aptr; u16* D = (u16*)Dptr;
    ln1_kernel<u16><<<dim3(128, 16), 256, 0, stream>>>(x, norm1_g, norm1_b, B, A);
    gemm_bt<768, 256, EPI_BIAS, u16, float><<<dim3(512, 6), 256, 0, stream>>>(B, inw_h, in_b, nullptr, Cb);
    attn_kernel<<<dim3(8, 1024), 256, 0, stream>>>(Cb, B);
    gemm_bt<256, 256, EPI_RES, u16, u16><<<dim3(512, 2), 256, 0, stream>>>(B, W2, b2v, A, D);
    ln2_kernel<u16><<<16384, 256, 0, stream>>>(D, norm2_g, norm2_b, B);
    gemm_bt<1024, 256, EPI_GELU, u16, float><<<dim3(512, 8), 256, 0, stream>>>(B, fc1_h, fc1_b, nullptr, Cb);
    gemm_bt<256, 1024, EPI_BIAS, u16, float><<<dim3(512, 2), 256, 0, stream>>>(Cb, fc2_h, fc2_b, nullptr, B);
    final_kernel<u16><<<2048, 256, 0, stream>>>(D, B, out);
  }
}

// Round 4
// 822.421 us; speedup vs baseline: 1.1716x; 1.1716x over previous
//
#include <hip/hip_runtime.h>

typedef unsigned short u16;
typedef unsigned int   u32;
typedef __bf16 bf16_t;
typedef bf16_t bf16x8 __attribute__((ext_vector_type(8)));
typedef float  f32x4  __attribute__((ext_vector_type(4)));

__device__ __forceinline__ float b2f(u16 u) {
  union { float f; u32 i; } v; v.i = ((u32)u) << 16; return v.f;
}
__device__ __forceinline__ u16 f2b(float f) {
  union { float f; u32 i; } v; v.f = f;
  u32 r = v.i + 0x7FFFu + ((v.i >> 16) & 1u);
  return (u16)(r >> 16);
}
__device__ __forceinline__ void ld4(const float* p, float* o) {
  const float4 v = *(const float4*)p; o[0]=v.x; o[1]=v.y; o[2]=v.z; o[3]=v.w;
}
__device__ __forceinline__ void ld4(const u16* p, float* o) {
  union { ushort4 v; u16 e[4]; } u; u.v = *(const ushort4*)p;
#pragma unroll
  for (int k = 0; k < 4; ++k) o[k] = b2f(u.e[k]);
}

// ---------------------------------------------------------------------------
// Prep kernels
// ---------------------------------------------------------------------------
__global__ void conv_w(const float* __restrict__ src, u16* __restrict__ dst, int n) {
  const int i = blockIdx.x * 256 + threadIdx.x;
  if (i < n) dst[i] = f2b(src[i]);
}

__global__ void prep_w2(const float* __restrict__ proj_w, const float* __restrict__ out_w,
                        u16* __restrict__ W2) {
  const int o = blockIdx.x, c = threadIdx.x;
  float acc = 0.f;
  for (int m = 0; m < 256; ++m)
    acc += proj_w[o*256 + m] * out_w[m*256 + c];
  W2[o*256 + c] = f2b(acc);
}

__global__ void prep_b2(const float* __restrict__ proj_w, const float* __restrict__ out_b,
                        const float* __restrict__ proj_b, float* __restrict__ b2v) {
  const int o = threadIdx.x;
  float acc = proj_b[o];
  for (int m = 0; m < 256; ++m) acc += proj_w[o*256 + m] * out_b[m];
  b2v[o] = acc;
}

// ---------------------------------------------------------------------------
// LN1 over C + shifted window partition. Block = half a (b,h) row (32 w).
// xn_tok bf16, x_tok bf16 (residual).
// ---------------------------------------------------------------------------
__global__ __launch_bounds__(256, 2)
void ln1_kernel(const float* __restrict__ x, const float* __restrict__ g,
                const float* __restrict__ bb, u16* __restrict__ xn_tok,
                u16* __restrict__ x_tok) {
  const int bx = blockIdx.x;                 // 128: h*2 + half
  const int h = bx >> 1, w0 = (bx & 1) << 5;
  const int b = blockIdx.y;
  const int tid = threadIdx.x;
  __shared__ float X[256][33];
  __shared__ float ps[8][32], pq[8][32];
  __shared__ float mu_s[32], rs_s[32];
  const int w = tid & 31, cg = tid >> 5;
  float sum = 0.f, sq = 0.f;
  const float* xb = x + ((size_t)b * 256) * 4096 + h * 64 + w0;
  for (int i = 0; i < 32; ++i) {
    const int c = i*8 + cg;
    const float v = xb[(size_t)c * 4096 + w];
    X[c][w] = v; sum += v; sq += v*v;
  }
  ps[cg][w] = sum; pq[cg][w] = sq;
  __syncthreads();
  if (tid < 32) {
    float s = 0.f, q2 = 0.f;
#pragma unroll
    for (int j = 0; j < 8; ++j) { s += ps[j][tid]; q2 += pq[j][tid]; }
    const float mu = s * (1.f/256.f);
    mu_s[tid] = mu;
    rs_s[tid] = rsqrtf(fmaxf(q2 * (1.f/256.f) - mu*mu, 0.f) + 1e-6f);
  }
  __syncthreads();
  const int c = tid;
  const float gc = g[c], bc = bb[c];
  const int hp = (h + 60) & 63;              // h' = (h-4) mod 64
  const int wi = hp >> 3, tr = hp & 7;
  const int tokb = (b << 6) + (wi << 3);
  for (int w2 = 0; w2 < 32; ++w2) {
    const int wp = (w0 + w2 + 60) & 63;
    const int tok = (tokb + (wp >> 3)) * 64 + tr*8 + (wp & 7);
    const float v = X[c][w2];
    xn_tok[(size_t)tok * 256 + c] = f2b((v - mu_s[w2]) * rs_s[w2] * gc + bc);
    x_tok [(size_t)tok * 256 + c] = f2b(v);
  }
}

// ---------------------------------------------------------------------------
// MFMA GEMM: C[M,N] = A[M,K] @ W[N,K]^T (+bias; +gelu | +residual(bf16)).
// 128x128 tile, BK=64, 4 waves. XOR-swizzled LDS staging.
// 1-D grid with XCD-aware remap: XCD (= id%8, m09) keeps one A row-block
// resident across all NB column blocks -> A fetched once from HBM.
// Epilogue: per-wave LDS transpose -> 16B contiguous stores.
// ---------------------------------------------------------------------------
constexpr int EPI_BIAS = 0, EPI_GELU = 1, EPI_RES = 2;

template<int N, int K, int NB, int EPI, typename OutT>
__global__ __launch_bounds__(256, 2)
void gemm_bt(const u16* __restrict__ A, const u16* __restrict__ W,
             const float* __restrict__ bias, const u16* __restrict__ res,
             OutT* __restrict__ C) {
  __shared__ u16 SMEM[2*128*64];             // 32 KB: As | Ws; reused by epilogue
  u16* As = SMEM;
  u16* Ws = SMEM + 128*64;
  const int tid = threadIdx.x;
  const int lane = tid & 63;
  const int wave = tid >> 6;
  const int wm = (wave >> 1) << 6;
  const int wn = (wave & 1) << 6;
  const int id = blockIdx.x;
  const int kk = id >> 3, xx = id & 7;
  const int bn = kk % NB;
  const int bm = (kk / NB) * 8 + xx;
  const u16* Ab = A + (size_t)bm * 128 * K;
  const u16* Wb = W + (size_t)bn * 128 * K;
  f32x4 acc[4][4] = {};

  for (int kb = 0; kb < K; kb += 64) {
    uint4 av[4], wv4[4];
#pragma unroll
    for (int e = 0; e < 4; ++e) {
      const int f = e*256 + tid;
      const int r = f >> 3, c = f & 7;
      av[e]  = *(const uint4*)(Ab + (size_t)r*K + kb + c*8);
      wv4[e] = *(const uint4*)(Wb + (size_t)r*K + kb + c*8);
    }
    __syncthreads();
#pragma unroll
    for (int e = 0; e < 4; ++e) {
      const int f = e*256 + tid;
      const int r = f >> 3, c = f & 7;
      const int p = c ^ (r & 7);
      *(uint4*)(As + r*64 + p*8) = av[e];
      *(uint4*)(Ws + r*64 + p*8) = wv4[e];
    }
    __syncthreads();
#pragma unroll
    for (int ks = 0; ks < 2; ++ks) {
      bf16x8 af[4], wf[4];
#pragma unroll
      for (int i = 0; i < 4; ++i) {
        const int ra = wm + i*16 + (lane & 15);
        const int pa = ((ks<<2) + (lane >> 4)) ^ (ra & 7);
        af[i] = *(const bf16x8*)(As + ra*64 + pa*8);
        const int rb = wn + i*16 + (lane & 15);
        const int pb = ((ks<<2) + (lane >> 4)) ^ (rb & 7);
        wf[i] = *(const bf16x8*)(Ws + rb*64 + pb*8);
      }
#pragma unroll
      for (int i = 0; i < 4; ++i)
#pragma unroll
        for (int j = 0; j < 4; ++j)
          acc[i][j] = __builtin_amdgcn_mfma_f32_16x16x32_bf16(af[i], wf[j], acc[i][j], 0, 0, 0);
    }
  }
  // ---- epilogue: LDS transpose to contiguous stores ----
  __syncthreads();                           // all waves done with As/Ws
  float* Es = (float*)SMEM + wave * (16*68); // 4 waves x 4352 B = 17 KB
  const int c0 = lane & 15, g4 = lane >> 4;
  float bj[4];
#pragma unroll
  for (int j = 0; j < 4; ++j) bj[j] = bias[bn*128 + wn + j*16 + c0];
#pragma unroll
  for (int i = 0; i < 4; ++i) {
#pragma unroll
    for (int j = 0; j < 4; ++j)
#pragma unroll
      for (int r = 0; r < 4; ++r) {
        float v = acc[i][j][r] + bj[j];      // C/D layout: col=lane&15, row=g4*4+r
        if constexpr (EPI == EPI_GELU)
          v = 0.5f * v * (1.f + erff(v * 0.7071067811865475f));
        Es[(g4*4 + r)*68 + j*16 + c0] = v;   // 2-way bank alias: free (m136)
      }
    // same-wave LDS write->read: compiler inserts lgkmcnt waits
#pragma unroll
    for (int t = 0; t < 2; ++t) {
      const int r16 = t*8 + (lane >> 3);
      const int cc = (lane & 7) * 8;
      const float* ep = Es + r16*68 + cc;
      float v[8];
#pragma unroll
      for (int k = 0; k < 8; ++k) v[k] = ep[k];
      const int row = bm*128 + wm + i*16 + r16;
      const int colg = bn*128 + wn + cc;
      if constexpr (EPI == EPI_RES) {
        union { uint4 q; u16 e[8]; } rv;
        rv.q = *(const uint4*)(res + (size_t)row * N + colg);
#pragma unroll
        for (int k = 0; k < 8; ++k) v[k] += b2f(rv.e[k]);
      }
      if constexpr (sizeof(OutT) == 2) {
        union { uint4 q; u16 e[8]; } ov;
#pragma unroll
        for (int k = 0; k < 8; ++k) ov.e[k] = f2b(v[k]);
        *(uint4*)((u16*)C + (size_t)row * N + colg) = ov.q;
      } else {
        float4 o0 = {v[0],v[1],v[2],v[3]}, o1 = {v[4],v[5],v[6],v[7]};
        float* cp = (float*)C + (size_t)row * N + colg;
        *(float4*)cp = o0; *(float4*)(cp + 4) = o1;
      }
    }
  }
}

// ---------------------------------------------------------------------------
// Attention: one block per (window, head). MFMA QK^T -> softmax (shfl) ->
// P via LDS -> MFMA PV -> O via LDS (reuse Qs) -> 16B stores.
// ---------------------------------------------------------------------------
__global__ __launch_bounds__(256, 2)
void attn_kernel(const u16* __restrict__ qkv, u16* __restrict__ attn) {
  const int h = blockIdx.x;       // head
  const int n = blockIdx.y;       // window
  const int tid = threadIdx.x;
  const int lane = tid & 63, wv = tid >> 6;
  __shared__ u16 Qs[64*40];
  __shared__ u16 Ks[64*40];
  __shared__ u16 Vt[32*72];       // V transposed [d][t]
  __shared__ u16 Ps[64*72];
  {
    const int row = tid >> 2, ch = tid & 3;
    const u16* base = qkv + (size_t)(n*64 + row) * 768 + h*32 + ch*8;
    *(uint4*)(Qs + row*40 + ch*8) = *(const uint4*)(base);
    *(uint4*)(Ks + row*40 + ch*8) = *(const uint4*)(base + 256);
    union { uint4 v; u16 e[8]; } tmp;
    tmp.v = *(const uint4*)(base + 512);
#pragma unroll
    for (int j = 0; j < 8; ++j) Vt[(ch*8 + j)*72 + row] = tmp.e[j];
  }
  __syncthreads();
  const int mrow = (wv << 4) + (lane & 15);
  const int q4 = lane >> 4;
  f32x4 s[4];
  {
    bf16x8 qa = *(const bf16x8*)(Qs + mrow*40 + q4*8);
#pragma unroll
    for (int nt = 0; nt < 4; ++nt) {
      bf16x8 kb = *(const bf16x8*)(Ks + (nt*16 + (lane & 15))*40 + q4*8);
      f32x4 z = {0.f, 0.f, 0.f, 0.f};
      s[nt] = __builtin_amdgcn_mfma_f32_16x16x32_bf16(qa, kb, z, 0, 0, 0);
    }
  }
  float pr[4][4];
#pragma unroll
  for (int r = 0; r < 4; ++r) {
    float m0 = fmaxf(fmaxf(s[0][r], s[1][r]), fmaxf(s[2][r], s[3][r]));
    m0 = fmaxf(m0, __shfl_xor(m0, 1, 64));
    m0 = fmaxf(m0, __shfl_xor(m0, 2, 64));
    m0 = fmaxf(m0, __shfl_xor(m0, 4, 64));
    m0 = fmaxf(m0, __shfl_xor(m0, 8, 64));
    const float cs = 0.25500526571944696f;  // log2(e)/sqrt(32)
    float p0 = exp2f(fminf((s[0][r] - m0) * cs, 0.f));
    float p1 = exp2f(fminf((s[1][r] - m0) * cs, 0.f));
    float p2 = exp2f(fminf((s[2][r] - m0) * cs, 0.f));
    float p3 = exp2f(fminf((s[3][r] - m0) * cs, 0.f));
    float sum = p0 + p1 + p2 + p3;
    sum += __shfl_xor(sum, 1, 64);
    sum += __shfl_xor(sum, 2, 64);
    sum += __shfl_xor(sum, 4, 64);
    sum += __shfl_xor(sum, 8, 64);
    const float inv = 1.f / sum;
    pr[0][r] = p0*inv; pr[1][r] = p1*inv; pr[2][r] = p2*inv; pr[3][r] = p3*inv;
  }
  {
    const int c = lane & 15;
#pragma unroll
    for (int nt = 0; nt < 4; ++nt)
#pragma unroll
      for (int r = 0; r < 4; ++r)
        Ps[((wv<<4) + (q4<<2) + r)*72 + nt*16 + c] = f2b(pr[nt][r]);
  }
  __syncthreads();
  f32x4 o0 = {0.f,0.f,0.f,0.f}, o1 = {0.f,0.f,0.f,0.f};
#pragma unroll
  for (int ks = 0; ks < 2; ++ks) {
    bf16x8 pa = *(const bf16x8*)(Ps + mrow*72 + ks*32 + q4*8);
    bf16x8 v0 = *(const bf16x8*)(Vt + (lane & 15)*72 + ks*32 + q4*8);
    bf16x8 v1 = *(const bf16x8*)(Vt + (16 + (lane & 15))*72 + ks*32 + q4*8);
    o0 = __builtin_amdgcn_mfma_f32_16x16x32_bf16(pa, v0, o0, 0, 0, 0);
    o1 = __builtin_amdgcn_mfma_f32_16x16x32_bf16(pa, v1, o1, 0, 0, 0);
  }
  // O staging in this wave's own Qs region (rows wv*16..wv*16+15) -> 16B stores
  {
    u16* Os = Qs + wv * 640;                 // 16 rows x stride 40
    const int c = lane & 15;
#pragma unroll
    for (int r = 0; r < 4; ++r) {
      Os[((q4<<2) + r)*40 + c]      = f2b(o0[r]);
      Os[((q4<<2) + r)*40 + 16 + c] = f2b(o1[r]);
    }
    const int rr = lane >> 2, d0 = (lane & 3) * 8;
    union { uint4 q; u16 e[8]; } ov;
#pragma unroll
    for (int k = 0; k < 8; ++k) ov.e[k] = Os[rr*40 + d0 + k];
    *(uint4*)(attn + (size_t)(n*64 + (wv<<4) + rr) * 256 + h*32 + d0) = ov.q;
  }
}

// ---------------------------------------------------------------------------
// LN2: token-major rows, one wave per token. y (f32|bf16) -> zn bf16.
// ---------------------------------------------------------------------------
template<typename YT>
__global__ __launch_bounds__(256, 4)
void ln2_kernel(const YT* __restrict__ y, const float* __restrict__ g,
                const float* __restrict__ bb, u16* __restrict__ zn) {
  const int t = blockIdx.x * 4 + (threadIdx.x >> 6);
  const int lane = threadIdx.x & 63;
  float f[4];
  ld4(y + (size_t)t*256 + lane*4, f);
  float sum = f[0]+f[1]+f[2]+f[3];
  float sq  = f[0]*f[0]+f[1]*f[1]+f[2]*f[2]+f[3]*f[3];
#pragma unroll
  for (int d = 32; d; d >>= 1) { sum += __shfl_xor(sum, d, 64); sq += __shfl_xor(sq, d, 64); }
  const float mu = sum * (1.f/256.f);
  const float rs = rsqrtf(fmaxf(sq * (1.f/256.f) - mu*mu, 0.f) + 1e-6f);
  const float4 gv = *(const float4*)(g + lane*4);
  const float4 bv = *(const float4*)(bb + lane*4);
  union { ushort4 v; u16 e[4]; } ov;
  ov.e[0] = f2b((f[0]-mu)*rs*gv.x + bv.x);
  ov.e[1] = f2b((f[1]-mu)*rs*gv.y + bv.y);
  ov.e[2] = f2b((f[2]-mu)*rs*gv.z + bv.z);
  ov.e[3] = f2b((f[3]-mu)*rs*gv.w + bv.w);
  *(ushort4*)(zn + (size_t)t*256 + lane*4) = ov.v;
}

// ---------------------------------------------------------------------------
// Final: out = y + z2 scattered back to image layout via LDS transpose.
// Block = half window (32 tokens).
// ---------------------------------------------------------------------------
template<typename YT>
__global__ __launch_bounds__(256, 2)
void final_kernel(const YT* __restrict__ y, const u16* __restrict__ z2,
                  float* __restrict__ out) {
  const int nb = blockIdx.x;              // 2048: window*2 + half
  const int n = nb >> 1, half = nb & 1;
  const int b = n >> 6, wi = (n >> 3) & 7, wj = n & 7;
  const int tid = threadIdx.x;
  __shared__ float S[256][33];
#pragma unroll
  for (int i = 0; i < 4; ++i) {
    const int flat = i*256 + tid;
    const int tl = flat >> 5, ch8 = flat & 31;
    const size_t off = (size_t)(n*64 + half*32 + tl) * 256 + ch8*8;
    float yv[8];
    ld4(y + off, yv); ld4(y + off + 4, yv + 4);
    union { uint4 v; u16 e[8]; } zv; zv.v = *(const uint4*)(z2 + off);
#pragma unroll
    for (int k = 0; k < 8; ++k)
      S[ch8*8 + k][tl] = yv[k] + b2f(zv.e[k]);
  }
  __syncthreads();
  const int c = tid;
  float* ob = out + ((size_t)(b*256 + c)) * 4096;
  const int w0 = (wj << 3) + 4;
  const int w1 = ((wj << 3) + 8) & 63;
#pragma unroll
  for (int trl = 0; trl < 4; ++trl) {
    const int hh = ((wi << 3) + (half << 2) + trl + 4) & 63;
    float4 p0, p1;
    p0.x = S[c][trl*8+0]; p0.y = S[c][trl*8+1]; p0.z = S[c][trl*8+2]; p0.w = S[c][trl*8+3];
    p1.x = S[c][trl*8+4]; p1.y = S[c][trl*8+5]; p1.z = S[c][trl*8+6]; p1.w = S[c][trl*8+7];
    *(float4*)(ob + hh*64 + w0) = p0;
    *(float4*)(ob + hh*64 + w1) = p1;
  }
}

// ---------------------------------------------------------------------------
extern "C" void kernel_launch(void* const* d_in, const int* in_sizes, int n_in,
                              void* d_out, int out_size, void* d_ws, size_t ws_size,
                              hipStream_t stream) {
  const float* x       = (const float*)d_in[0];
  const float* norm1_g = (const float*)d_in[1];
  const float* norm1_b = (const float*)d_in[2];
  const float* in_w    = (const float*)d_in[3];
  const float* in_b    = (const float*)d_in[4];
  const float* out_w   = (const float*)d_in[5];
  const float* out_b   = (const float*)d_in[6];
  const float* proj_w  = (const float*)d_in[7];
  const float* proj_b  = (const float*)d_in[8];
  const float* norm2_g = (const float*)d_in[9];
  const float* norm2_b = (const float*)d_in[10];
  const float* fc1_w   = (const float*)d_in[11];
  const float* fc1_b   = (const float*)d_in[12];
  const float* fc2_w   = (const float*)d_in[13];
  const float* fc2_b   = (const float*)d_in[14];
  float* out = (float*)d_out;

  const size_t nA = 16777216;             // 65536 tokens x 256 ch

  char* base = (char*)d_ws;
  const bool yf32 = ws_size >= 270009344ull;   // y in f32 if it fits

  u16* A  = (u16*)base;                   // x_tok bf16
  u16* B  = (u16*)(base + nA*2);          // xn -> attn-out -> zn -> z2
  u16* Cb = (u16*)(base + nA*4);          // qkv (3nA) -> h1 (4nA)
  char* Dp = base + nA*4 + nA*8;          // y: f32 or bf16
  char* Wp = Dp + (yf32 ? nA*4 : nA*2);
  u16* W2    = (u16*)Wp;                  // 65536
  u16* inw_h = W2 + 65536;                // 196608
  u16* fc1_h = inw_h + 196608;            // 262144
  u16* fc2_h = fc1_h + 262144;            // 262144
  float* b2v = (float*)(fc2_h + 262144);  // 256

  conv_w<<<768, 256, 0, stream>>>(in_w, inw_h, 196608);
  conv_w<<<1024, 256, 0, stream>>>(fc1_w, fc1_h, 262144);
  conv_w<<<1024, 256, 0, stream>>>(fc2_w, fc2_h, 262144);
  prep_w2<<<256, 256, 0, stream>>>(proj_w, out_w, W2);
  prep_b2<<<1, 256, 0, stream>>>(proj_w, out_b, proj_b, b2v);

  ln1_kernel<<<dim3(128, 16), 256, 0, stream>>>(x, norm1_g, norm1_b, B, A);
  // qkv = xn @ in_w^T + in_b   (65536 x 768 x 256), NB=6
  gemm_bt<768, 256, 6, EPI_BIAS, u16><<<3072, 256, 0, stream>>>(B, inw_h, in_b, nullptr, Cb);
  attn_kernel<<<dim3(8, 1024), 256, 0, stream>>>(Cb, B);
  if (yf32) {
    float* D = (float*)Dp;
    gemm_bt<256, 256, 2, EPI_RES, float><<<1024, 256, 0, stream>>>(B, W2, b2v, A, D);
    ln2_kernel<float><<<16384, 256, 0, stream>>>(D, norm2_g, norm2_b, B);
  } else {
    u16* D = (u16*)Dp;
    gemm_bt<256, 256, 2, EPI_RES, u16><<<1024, 256, 0, stream>>>(B, W2, b2v, A, D);
    ln2_kernel<u16><<<16384, 256, 0, stream>>>(D, norm2_g, norm2_b, B);
  }
  // h1 = gelu(zn @ fc1^T + b)  (65536 x 1024 x 256), NB=8
  gemm_bt<1024, 256, 8, EPI_GELU, u16><<<4096, 256, 0, stream>>>(B, fc1_h, fc1_b, nullptr, Cb);
  // z2 = h1 @ fc2^T + b        (65536 x 256 x 1024), NB=2
  gemm_bt<256, 1024, 2, EPI_BIAS, u16><<<1024, 256, 0, stream>>>(Cb, fc2_h, fc2_b, nullptr, B);
  if (yf32) final_kernel<float><<<2048, 256, 0, stream>>>((float*)Dp, B, out);
  else      final_kernel<u16><<<2048, 256, 0, stream>>>((u16*)Dp, B, out);
}

// Round 5
// 771.628 us; speedup vs baseline: 1.2487x; 1.0658x over previous
//
#include <hip/hip_runtime.h>

typedef unsigned short u16;
typedef unsigned int   u32;
typedef __bf16 bf16_t;
typedef bf16_t bf16x8 __attribute__((ext_vector_type(8)));
typedef float  f32x4  __attribute__((ext_vector_type(4)));

__device__ __forceinline__ float b2f(u16 u) {
  union { float f; u32 i; } v; v.i = ((u32)u) << 16; return v.f;
}
__device__ __forceinline__ u16 f2b(float f) {
  union { float f; u32 i; } v; v.f = f;
  u32 r = v.i + 0x7FFFu + ((v.i >> 16) & 1u);
  return (u16)(r >> 16);
}
__device__ __forceinline__ void ld4(const float* p, float* o) {
  const float4 v = *(const float4*)p; o[0]=v.x; o[1]=v.y; o[2]=v.z; o[3]=v.w;
}
__device__ __forceinline__ void ld4(const u16* p, float* o) {
  union { ushort4 v; u16 e[4]; } u; u.v = *(const ushort4*)p;
#pragma unroll
  for (int k = 0; k < 4; ++k) o[k] = b2f(u.e[k]);
}
__device__ __forceinline__ float ld1(const float* p) { return *p; }
__device__ __forceinline__ float ld1(const u16* p)   { return b2f(*p); }

// ---------------------------------------------------------------------------
// Prep kernels
// ---------------------------------------------------------------------------
__global__ void conv_w(const float* __restrict__ src, u16* __restrict__ dst, int n) {
  const int i = blockIdx.x * 256 + threadIdx.x;
  if (i < n) dst[i] = f2b(src[i]);
}

__global__ void prep_w2(const float* __restrict__ proj_w, const float* __restrict__ out_w,
                        u16* __restrict__ W2) {
  const int o = blockIdx.x, c = threadIdx.x;
  float acc = 0.f;
  for (int m = 0; m < 256; ++m)
    acc += proj_w[o*256 + m] * out_w[m*256 + c];
  W2[o*256 + c] = f2b(acc);
}

__global__ void prep_b2(const float* __restrict__ proj_w, const float* __restrict__ out_b,
                        const float* __restrict__ proj_b, float* __restrict__ b2v) {
  const int o = threadIdx.x;
  float acc = proj_b[o];
  for (int m = 0; m < 256; ++m) acc += proj_w[o*256 + m] * out_b[m];
  b2v[o] = acc;
}

// ---------------------------------------------------------------------------
// LN1 over C + shifted window partition.
// ---------------------------------------------------------------------------
__global__ __launch_bounds__(256, 2)
void ln1_kernel(const float* __restrict__ x, const float* __restrict__ g,
                const float* __restrict__ bb, u16* __restrict__ xn_tok,
                u16* __restrict__ x_tok) {
  const int bx = blockIdx.x;                 // 128: h*2 + half
  const int h = bx >> 1, w0 = (bx & 1) << 5;
  const int b = blockIdx.y;
  const int tid = threadIdx.x;
  __shared__ float X[256][33];
  __shared__ float ps[8][32], pq[8][32];
  __shared__ float mu_s[32], rs_s[32];
  const int w = tid & 31, cg = tid >> 5;
  float sum = 0.f, sq = 0.f;
  const float* xb = x + ((size_t)b * 256) * 4096 + h * 64 + w0;
  for (int i = 0; i < 32; ++i) {
    const int c = i*8 + cg;
    const float v = xb[(size_t)c * 4096 + w];
    X[c][w] = v; sum += v; sq += v*v;
  }
  ps[cg][w] = sum; pq[cg][w] = sq;
  __syncthreads();
  if (tid < 32) {
    float s = 0.f, q2 = 0.f;
#pragma unroll
    for (int j = 0; j < 8; ++j) { s += ps[j][tid]; q2 += pq[j][tid]; }
    const float mu = s * (1.f/256.f);
    mu_s[tid] = mu;
    rs_s[tid] = rsqrtf(fmaxf(q2 * (1.f/256.f) - mu*mu, 0.f) + 1e-6f);
  }
  __syncthreads();
  const int c = tid;
  const float gc = g[c], bc = bb[c];
  const int hp = (h + 60) & 63;              // h' = (h-4) mod 64
  const int wi = hp >> 3, tr = hp & 7;
  const int tokb = (b << 6) + (wi << 3);
  for (int w2 = 0; w2 < 32; ++w2) {
    const int wp = (w0 + w2 + 60) & 63;
    const int tok = (tokb + (wp >> 3)) * 64 + tr*8 + (wp & 7);
    const float v = X[c][w2];
    xn_tok[(size_t)tok * 256 + c] = f2b((v - mu_s[w2]) * rs_s[w2] * gc + bc);
    x_tok [(size_t)tok * 256 + c] = f2b(v);
  }
}

// ---------------------------------------------------------------------------
// MFMA GEMM (qkv and attn-proj+residual): C = A @ W^T (+bias; +res).
// 128x128 tile, BK=64, XOR-swizzled LDS, XCD remap, LDS-transpose epilogue.
// ---------------------------------------------------------------------------
constexpr int EPI_BIAS = 0, EPI_RES = 2;

template<int N, int K, int NB, int EPI, typename OutT>
__global__ __launch_bounds__(256, 2)
void gemm_bt(const u16* __restrict__ A, const u16* __restrict__ W,
             const float* __restrict__ bias, const u16* __restrict__ res,
             OutT* __restrict__ C) {
  __shared__ u16 SMEM[2*128*64];
  u16* As = SMEM;
  u16* Ws = SMEM + 128*64;
  const int tid = threadIdx.x;
  const int lane = tid & 63;
  const int wave = tid >> 6;
  const int wm = (wave >> 1) << 6;
  const int wn = (wave & 1) << 6;
  const int id = blockIdx.x;
  const int kk = id >> 3, xx = id & 7;
  const int bn = kk % NB;
  const int bm = (kk / NB) * 8 + xx;
  const u16* Ab = A + (size_t)bm * 128 * K;
  const u16* Wb = W + (size_t)bn * 128 * K;
  f32x4 acc[4][4] = {};

  for (int kb = 0; kb < K; kb += 64) {
    uint4 av[4], wv4[4];
#pragma unroll
    for (int e = 0; e < 4; ++e) {
      const int f = e*256 + tid;
      const int r = f >> 3, c = f & 7;
      av[e]  = *(const uint4*)(Ab + (size_t)r*K + kb + c*8);
      wv4[e] = *(const uint4*)(Wb + (size_t)r*K + kb + c*8);
    }
    __syncthreads();
#pragma unroll
    for (int e = 0; e < 4; ++e) {
      const int f = e*256 + tid;
      const int r = f >> 3, c = f & 7;
      const int p = c ^ (r & 7);
      *(uint4*)(As + r*64 + p*8) = av[e];
      *(uint4*)(Ws + r*64 + p*8) = wv4[e];
    }
    __syncthreads();
#pragma unroll
    for (int ks = 0; ks < 2; ++ks) {
      bf16x8 af[4], wf[4];
#pragma unroll
      for (int i = 0; i < 4; ++i) {
        const int ra = wm + i*16 + (lane & 15);
        const int pa = ((ks<<2) + (lane >> 4)) ^ (ra & 7);
        af[i] = *(const bf16x8*)(As + ra*64 + pa*8);
        const int rb = wn + i*16 + (lane & 15);
        const int pb = ((ks<<2) + (lane >> 4)) ^ (rb & 7);
        wf[i] = *(const bf16x8*)(Ws + rb*64 + pb*8);
      }
#pragma unroll
      for (int i = 0; i < 4; ++i)
#pragma unroll
        for (int j = 0; j < 4; ++j)
          acc[i][j] = __builtin_amdgcn_mfma_f32_16x16x32_bf16(af[i], wf[j], acc[i][j], 0, 0, 0);
    }
  }
  __syncthreads();
  float* Es = (float*)SMEM + wave * (16*68);
  const int c0 = lane & 15, g4 = lane >> 4;
  float bj[4];
#pragma unroll
  for (int j = 0; j < 4; ++j) bj[j] = bias[bn*128 + wn + j*16 + c0];
#pragma unroll
  for (int i = 0; i < 4; ++i) {
#pragma unroll
    for (int j = 0; j < 4; ++j)
#pragma unroll
      for (int r = 0; r < 4; ++r) {
        float v = acc[i][j][r] + bj[j];
        Es[(g4*4 + r)*68 + j*16 + c0] = v;
      }
#pragma unroll
    for (int t = 0; t < 2; ++t) {
      const int r16 = t*8 + (lane >> 3);
      const int cc = (lane & 7) * 8;
      const float* ep = Es + r16*68 + cc;
      float v[8];
#pragma unroll
      for (int k = 0; k < 8; ++k) v[k] = ep[k];
      const int row = bm*128 + wm + i*16 + r16;
      const int colg = bn*128 + wn + cc;
      if constexpr (EPI == EPI_RES) {
        union { uint4 q; u16 e[8]; } rv;
        rv.q = *(const uint4*)(res + (size_t)row * N + colg);
#pragma unroll
        for (int k = 0; k < 8; ++k) v[k] += b2f(rv.e[k]);
      }
      if constexpr (sizeof(OutT) == 2) {
        union { uint4 q; u16 e[8]; } ov;
#pragma unroll
        for (int k = 0; k < 8; ++k) ov.e[k] = f2b(v[k]);
        *(uint4*)((u16*)C + (size_t)row * N + colg) = ov.q;
      } else {
        float4 o0 = {v[0],v[1],v[2],v[3]}, o1 = {v[4],v[5],v[6],v[7]};
        float* cp = (float*)C + (size_t)row * N + colg;
        *(float4*)cp = o0; *(float4*)(cp + 4) = o1;
      }
    }
  }
}

// ---------------------------------------------------------------------------
// Attention: one block per (window, head).
// ---------------------------------------------------------------------------
__global__ __launch_bounds__(256, 2)
void attn_kernel(const u16* __restrict__ qkv, u16* __restrict__ attn) {
  const int h = blockIdx.x;
  const int n = blockIdx.y;
  const int tid = threadIdx.x;
  const int lane = tid & 63, wv = tid >> 6;
  __shared__ u16 Qs[64*40];
  __shared__ u16 Ks[64*40];
  __shared__ u16 Vt[32*72];
  __shared__ u16 Ps[64*72];
  {
    const int row = tid >> 2, ch = tid & 3;
    const u16* base = qkv + (size_t)(n*64 + row) * 768 + h*32 + ch*8;
    *(uint4*)(Qs + row*40 + ch*8) = *(const uint4*)(base);
    *(uint4*)(Ks + row*40 + ch*8) = *(const uint4*)(base + 256);
    union { uint4 v; u16 e[8]; } tmp;
    tmp.v = *(const uint4*)(base + 512);
#pragma unroll
    for (int j = 0; j < 8; ++j) Vt[(ch*8 + j)*72 + row] = tmp.e[j];
  }
  __syncthreads();
  const int mrow = (wv << 4) + (lane & 15);
  const int q4 = lane >> 4;
  f32x4 s[4];
  {
    bf16x8 qa = *(const bf16x8*)(Qs + mrow*40 + q4*8);
#pragma unroll
    for (int nt = 0; nt < 4; ++nt) {
      bf16x8 kb = *(const bf16x8*)(Ks + (nt*16 + (lane & 15))*40 + q4*8);
      f32x4 z = {0.f, 0.f, 0.f, 0.f};
      s[nt] = __builtin_amdgcn_mfma_f32_16x16x32_bf16(qa, kb, z, 0, 0, 0);
    }
  }
  float pr[4][4];
#pragma unroll
  for (int r = 0; r < 4; ++r) {
    float m0 = fmaxf(fmaxf(s[0][r], s[1][r]), fmaxf(s[2][r], s[3][r]));
    m0 = fmaxf(m0, __shfl_xor(m0, 1, 64));
    m0 = fmaxf(m0, __shfl_xor(m0, 2, 64));
    m0 = fmaxf(m0, __shfl_xor(m0, 4, 64));
    m0 = fmaxf(m0, __shfl_xor(m0, 8, 64));
    const float cs = 0.25500526571944696f;  // log2(e)/sqrt(32)
    float p0 = exp2f(fminf((s[0][r] - m0) * cs, 0.f));
    float p1 = exp2f(fminf((s[1][r] - m0) * cs, 0.f));
    float p2 = exp2f(fminf((s[2][r] - m0) * cs, 0.f));
    float p3 = exp2f(fminf((s[3][r] - m0) * cs, 0.f));
    float sum = p0 + p1 + p2 + p3;
    sum += __shfl_xor(sum, 1, 64);
    sum += __shfl_xor(sum, 2, 64);
    sum += __shfl_xor(sum, 4, 64);
    sum += __shfl_xor(sum, 8, 64);
    const float inv = 1.f / sum;
    pr[0][r] = p0*inv; pr[1][r] = p1*inv; pr[2][r] = p2*inv; pr[3][r] = p3*inv;
  }
  {
    const int c = lane & 15;
#pragma unroll
    for (int nt = 0; nt < 4; ++nt)
#pragma unroll
      for (int r = 0; r < 4; ++r)
        Ps[((wv<<4) + (q4<<2) + r)*72 + nt*16 + c] = f2b(pr[nt][r]);
  }
  __syncthreads();
  f32x4 o0 = {0.f,0.f,0.f,0.f}, o1 = {0.f,0.f,0.f,0.f};
#pragma unroll
  for (int ks = 0; ks < 2; ++ks) {
    bf16x8 pa = *(const bf16x8*)(Ps + mrow*72 + ks*32 + q4*8);
    bf16x8 v0 = *(const bf16x8*)(Vt + (lane & 15)*72 + ks*32 + q4*8);
    bf16x8 v1 = *(const bf16x8*)(Vt + (16 + (lane & 15))*72 + ks*32 + q4*8);
    o0 = __builtin_amdgcn_mfma_f32_16x16x32_bf16(pa, v0, o0, 0, 0, 0);
    o1 = __builtin_amdgcn_mfma_f32_16x16x32_bf16(pa, v1, o1, 0, 0, 0);
  }
  {
    u16* Os = Qs + wv * 640;
    const int c = lane & 15;
#pragma unroll
    for (int r = 0; r < 4; ++r) {
      Os[((q4<<2) + r)*40 + c]      = f2b(o0[r]);
      Os[((q4<<2) + r)*40 + 16 + c] = f2b(o1[r]);
    }
    const int rr = lane >> 2, d0 = (lane & 3) * 8;
    union { uint4 q; u16 e[8]; } ov;
#pragma unroll
    for (int k = 0; k < 8; ++k) ov.e[k] = Os[rr*40 + d0 + k];
    *(uint4*)(attn + (size_t)(n*64 + (wv<<4) + rr) * 256 + h*32 + d0) = ov.q;
  }
}

// ---------------------------------------------------------------------------
// LN2: one wave per token. y (f32|bf16) -> zn bf16.
// ---------------------------------------------------------------------------
template<typename YT>
__global__ __launch_bounds__(256, 4)
void ln2_kernel(const YT* __restrict__ y, const float* __restrict__ g,
                const float* __restrict__ bb, u16* __restrict__ zn) {
  const int t = blockIdx.x * 4 + (threadIdx.x >> 6);
  const int lane = threadIdx.x & 63;
  float f[4];
  ld4(y + (size_t)t*256 + lane*4, f);
  float sum = f[0]+f[1]+f[2]+f[3];
  float sq  = f[0]*f[0]+f[1]*f[1]+f[2]*f[2]+f[3]*f[3];
#pragma unroll
  for (int d = 32; d; d >>= 1) { sum += __shfl_xor(sum, d, 64); sq += __shfl_xor(sq, d, 64); }
  const float mu = sum * (1.f/256.f);
  const float rs = rsqrtf(fmaxf(sq * (1.f/256.f) - mu*mu, 0.f) + 1e-6f);
  const float4 gv = *(const float4*)(g + lane*4);
  const float4 bv = *(const float4*)(bb + lane*4);
  union { ushort4 v; u16 e[4]; } ov;
  ov.e[0] = f2b((f[0]-mu)*rs*gv.x + bv.x);
  ov.e[1] = f2b((f[1]-mu)*rs*gv.y + bv.y);
  ov.e[2] = f2b((f[2]-mu)*rs*gv.z + bv.z);
  ov.e[3] = f2b((f[3]-mu)*rs*gv.w + bv.w);
  *(ushort4*)(zn + (size_t)t*256 + lane*4) = ov.v;
}

// ---------------------------------------------------------------------------
// Fused MLP: z2 = gelu(zn @ fc1^T + b1) @ fc2^T + b2; out = y + z2 scattered
// to image layout (window reverse + shift). Block = 1 window (64 tokens).
// h1 never leaves the CU. LDS 80 KB -> 2 blocks/CU.
//   region A  : zn tile 64x256 bf16, resident, XOR-swizzled (32 KB)
//   region W1P: W1 BK-chunk 128x64 (16 KB), later P tile 64x128 (16 KB)
//   region W2 : fc2 k-chunk 256x64 (32 KB)
//   epilogue F: f32 [256][33] overlays A+W1P
// ---------------------------------------------------------------------------
template<typename YT>
__global__ __launch_bounds__(256, 2)
void mlp_kernel(const u16* __restrict__ zn, const u16* __restrict__ W1,
                const float* __restrict__ b1, const u16* __restrict__ W2f,
                const float* __restrict__ b2, const YT* __restrict__ y,
                float* __restrict__ out) {
  __shared__ char SMEM[81920];
  u16* AsP  = (u16*)SMEM;                 // 32768 B
  u16* W1sP = (u16*)(SMEM + 32768);       // 16384 B (P tile overlays this)
  u16* SW2p = (u16*)(SMEM + 49152);       // 32768 B
  const int tid = threadIdx.x;
  const int lane = tid & 63;
  const int wave = tid >> 6;
  const int c0 = lane & 15, quad = lane >> 4;
  const int wm  = (wave >> 1) * 32;       // token rows (phase1, phase2, z2)
  const int wn1 = (wave & 1) * 64;        // hidden cols (phase1)
  const int wn2 = (wave & 1) * 128;       // out channels (phase2)
  const int n = blockIdx.x;               // window
  const int t0 = n * 64;

  // stage resident zn A-tile (64 x 256)
#pragma unroll
  for (int e = 0; e < 8; ++e) {
    const int f = e*256 + tid;
    const int r = f >> 5, c32 = f & 31;
    const int kb = c32 >> 3, c = c32 & 7;
    *(uint4*)(AsP + r*256 + kb*64 + ((c ^ (r & 7)))*8) =
        *(const uint4*)(zn + (size_t)(t0 + r)*256 + c32*8);
  }

  float b2j[8];
#pragma unroll
  for (int j = 0; j < 8; ++j) b2j[j] = b2[wn2 + j*16 + c0];

  f32x4 acc2[2][8] = {};

  for (int hb = 0; hb < 8; ++hb) {
    f32x4 acc1[2][4] = {};
    float b1j[4];
#pragma unroll
    for (int j = 0; j < 4; ++j) b1j[j] = b1[hb*128 + wn1 + j*16 + c0];
    // ---- phase 1: S = zn @ W1_hb^T, K=256 in 4 chunks ----
    for (int kb = 0; kb < 4; ++kb) {
      uint4 wv4[4];
#pragma unroll
      for (int e = 0; e < 4; ++e) {
        const int f = e*256 + tid;
        const int r = f >> 3, c = f & 7;
        wv4[e] = *(const uint4*)(W1 + (size_t)(hb*128 + r)*256 + kb*64 + c*8);
      }
      __syncthreads();                     // prev readers of W1sP/P done
#pragma unroll
      for (int e = 0; e < 4; ++e) {
        const int f = e*256 + tid;
        const int r = f >> 3, c = f & 7;
        *(uint4*)(W1sP + r*64 + (c ^ (r & 7))*8) = wv4[e];
      }
      __syncthreads();
#pragma unroll
      for (int ks = 0; ks < 2; ++ks) {
        const int ch = ks*4 + quad;
        bf16x8 af[2], wf[4];
#pragma unroll
        for (int i = 0; i < 2; ++i) {
          const int ra = wm + i*16 + c0;
          af[i] = *(const bf16x8*)(AsP + ra*256 + kb*64 + (ch ^ (ra & 7))*8);
        }
#pragma unroll
        for (int j = 0; j < 4; ++j) {
          const int rb = wn1 + j*16 + c0;
          wf[j] = *(const bf16x8*)(W1sP + rb*64 + (ch ^ (rb & 7))*8);
        }
#pragma unroll
        for (int i = 0; i < 2; ++i)
#pragma unroll
          for (int j = 0; j < 4; ++j)
            acc1[i][j] = __builtin_amdgcn_mfma_f32_16x16x32_bf16(af[i], wf[j], acc1[i][j], 0, 0, 0);
      }
    }
    // ---- gelu -> P tile (A-layout, swizzled) into W1sP region ----
    __syncthreads();                       // all waves done reading W1sP
#pragma unroll
    for (int i = 0; i < 2; ++i)
#pragma unroll
      for (int j = 0; j < 4; ++j)
#pragma unroll
        for (int r = 0; r < 4; ++r) {
          const int R = wm + i*16 + quad*4 + r;     // token row
          const int kcol = wn1 + j*16 + c0;         // hidden col (local)
          float v = acc1[i][j][r] + b1j[j];
          v = 0.5f * v * (1.f + erff(v * 0.7071067811865475f));
          W1sP[R*128 + (kcol >> 6)*64 + (((kcol >> 3) & 7) ^ (R & 7))*8 + (kcol & 7)] = f2b(v);
        }
    // ---- phase 2: z2 += P @ W2_hb^T, k=128 in 2 chunks ----
    for (int kb2 = 0; kb2 < 2; ++kb2) {
      uint4 wv4[8];
#pragma unroll
      for (int e = 0; e < 8; ++e) {
        const int f = e*256 + tid;
        const int r = f >> 3, c = f & 7;
        wv4[e] = *(const uint4*)(W2f + (size_t)r*1024 + hb*128 + kb2*64 + c*8);
      }
      __syncthreads();                     // P visible; prev SW2 readers done
#pragma unroll
      for (int e = 0; e < 8; ++e) {
        const int f = e*256 + tid;
        const int r = f >> 3, c = f & 7;
        *(uint4*)(SW2p + r*64 + (c ^ (r & 7))*8) = wv4[e];
      }
      __syncthreads();
#pragma unroll
      for (int ks = 0; ks < 2; ++ks) {
        const int ch = ks*4 + quad;
        bf16x8 pf[2], vf[8];
#pragma unroll
        for (int i = 0; i < 2; ++i) {
          const int ra = wm + i*16 + c0;
          pf[i] = *(const bf16x8*)(W1sP + ra*128 + kb2*64 + (ch ^ (ra & 7))*8);
        }
#pragma unroll
        for (int j = 0; j < 8; ++j) {
          const int rb = wn2 + j*16 + c0;
          vf[j] = *(const bf16x8*)(SW2p + rb*64 + (ch ^ (rb & 7))*8);
        }
#pragma unroll
        for (int i = 0; i < 2; ++i)
#pragma unroll
          for (int j = 0; j < 8; ++j)
            acc2[i][j] = __builtin_amdgcn_mfma_f32_16x16x32_bf16(pf[i], vf[j], acc2[i][j], 0, 0, 0);
      }
    }
  }
  // ---- epilogue: out = y + z2, window-reverse + shift scatter ----
  float* F = (float*)SMEM;                 // [256][33] f32 = 33.8 KB
  const int b = n >> 6, wi = (n >> 3) & 7, wj = n & 7;
  const int w0 = (wj << 3) + 4;
  const int w1 = ((wj << 3) + 8) & 63;
  float* ob = out + ((size_t)(b*256 + tid)) * 4096;
  for (int q = 0; q < 2; ++q) {
    __syncthreads();                       // phase2 reads / prev stores done
    if ((wave >> 1) == q) {
#pragma unroll
      for (int i = 0; i < 2; ++i)
#pragma unroll
        for (int j = 0; j < 8; ++j)
#pragma unroll
          for (int r = 0; r < 4; ++r) {
            const int tl = i*16 + quad*4 + r;       // 0..31
            const int Cl = wn2 + j*16 + c0;
            const float v = acc2[i][j][r] + b2j[j]
                + ld1(y + (size_t)(t0 + q*32 + tl)*256 + Cl);
            F[Cl*33 + tl] = v;
          }
    }
    __syncthreads();
#pragma unroll
    for (int trl = 0; trl < 4; ++trl) {
      const int hh = ((wi << 3) + (q << 2) + trl + 4) & 63;
      const float* fp = F + tid*33 + trl*8;
      float4 p0 = {fp[0], fp[1], fp[2], fp[3]};
      float4 p1 = {fp[4], fp[5], fp[6], fp[7]};
      *(float4*)(ob + hh*64 + w0) = p0;
      *(float4*)(ob + hh*64 + w1) = p1;
    }
  }
}

// ---------------------------------------------------------------------------
extern "C" void kernel_launch(void* const* d_in, const int* in_sizes, int n_in,
                              void* d_out, int out_size, void* d_ws, size_t ws_size,
                              hipStream_t stream) {
  const float* x       = (const float*)d_in[0];
  const float* norm1_g = (const float*)d_in[1];
  const float* norm1_b = (const float*)d_in[2];
  const float* in_w    = (const float*)d_in[3];
  const float* in_b    = (const float*)d_in[4];
  const float* out_w   = (const float*)d_in[5];
  const float* out_b   = (const float*)d_in[6];
  const float* proj_w  = (const float*)d_in[7];
  const float* proj_b  = (const float*)d_in[8];
  const float* norm2_g = (const float*)d_in[9];
  const float* norm2_b = (const float*)d_in[10];
  const float* fc1_w   = (const float*)d_in[11];
  const float* fc1_b   = (const float*)d_in[12];
  const float* fc2_w   = (const float*)d_in[13];
  const float* fc2_b   = (const float*)d_in[14];
  float* out = (float*)d_out;

  const size_t nA = 16777216;             // 65536 tokens x 256 ch

  char* base = (char*)d_ws;
  // yf32 tier total: A 2nA + B 2nA + Cb 6nA + D 4nA + weights
  const bool yf32 = ws_size >= (14*nA + 1573888 + 1024);

  u16* A  = (u16*)base;                   // x_tok bf16
  u16* B  = (u16*)(base + nA*2);          // xn -> attn-out -> zn
  u16* Cb = (u16*)(base + nA*4);          // qkv (3nA elems)
  char* Dp = base + nA*4 + nA*6;          // y: f32 or bf16
  char* Wp = Dp + (yf32 ? nA*4 : nA*2);
  u16* W2    = (u16*)Wp;                  // 65536
  u16* inw_h = W2 + 65536;                // 196608
  u16* fc1_h = inw_h + 196608;            // 262144
  u16* fc2_h = fc1_h + 262144;            // 262144
  float* b2v = (float*)(fc2_h + 262144);  // 256

  conv_w<<<768, 256, 0, stream>>>(in_w, inw_h, 196608);
  conv_w<<<1024, 256, 0, stream>>>(fc1_w, fc1_h, 262144);
  conv_w<<<1024, 256, 0, stream>>>(fc2_w, fc2_h, 262144);
  prep_w2<<<256, 256, 0, stream>>>(proj_w, out_w, W2);
  prep_b2<<<1, 256, 0, stream>>>(proj_w, out_b, proj_b, b2v);

  ln1_kernel<<<dim3(128, 16), 256, 0, stream>>>(x, norm1_g, norm1_b, B, A);
  // qkv = xn @ in_w^T + in_b   (65536 x 768 x 256), NB=6
  gemm_bt<768, 256, 6, EPI_BIAS, u16><<<3072, 256, 0, stream>>>(B, inw_h, in_b, nullptr, Cb);
  attn_kernel<<<dim3(8, 1024), 256, 0, stream>>>(Cb, B);
  if (yf32) {
    float* D = (float*)Dp;
    gemm_bt<256, 256, 2, EPI_RES, float><<<1024, 256, 0, stream>>>(B, W2, b2v, A, D);
    ln2_kernel<float><<<16384, 256, 0, stream>>>(D, norm2_g, norm2_b, B);
    mlp_kernel<float><<<1024, 256, 0, stream>>>(B, fc1_h, fc1_b, fc2_h, fc2_b, D, out);
  } else {
    u16* D = (u16*)Dp;
    gemm_bt<256, 256, 2, EPI_RES, u16><<<1024, 256, 0, stream>>>(B, W2, b2v, A, D);
    ln2_kernel<u16><<<16384, 256, 0, stream>>>(D, norm2_g, norm2_b, B);
    mlp_kernel<u16><<<1024, 256, 0, stream>>>(B, fc1_h, fc1_b, fc2_h, fc2_b, D, out);
  }
}